// Round 4
// baseline (12027.713 us; speedup 1.0000x reference)
//
#include <hip/hip_runtime.h>
#include <math.h>

// UKF, one block/trajectory, 512 threads. R6: latency-bound fix — R5 starved
// waves (T/Pz/K/M on 128-136 thr, GJ serial). R6 keeps R4 algorithmics
// (T=H@Pn, f4 layout, fused writeback) but every phase uses all 8 waves and
// every serial section is overlapped:
//   A: panel0(w0) || stage F^T(w1-7)
//   B: rank-32 trailing (all 512)
//   C: panel1(w0) || FL cols 0..31 (w1-6) || Fx (w7)
//   D: FL cols 32..63 (all, 32-deep)
//   E: sigma + x_pred partials (all)
//   F: combine+center fused (all 512; xp recomputed per column-group; d0 -> sd0)
//   G: Pn Q-less, 2x4 tiles (all 512)
//   H: T = H@Pn (all 512)            I: Pz = T@H^T + R (all 512)
//   J: GJ(w0) || innovation(w1) || P+=Q f4 (w2-7)
//   K: K = Pxz@Pzinv stored TRANSPOSED (all 512)
//   L: M full (no tri; 2x4 tiles, all 512) fused with P_new/outP; x_new on w0
// 12 barriers/step. Bank conflicts measured ~2% of cycles — f4 strides kept.

#define NTRAJ 128
#define TSTEPS 250
#define NS 64
#define NO 32
#define PS 68    // P row stride
#define SFS 68   // sigma buffer row stride
#define HTS 36   // H^T row stride (row j holds H[:,j])
#define TS 68    // T = H@Pn row stride (row m = Pxz[:,m])
#define GJS 68   // Pz stride
#define PZS 36   // Pzinv col-major stride
#define KTS 68   // K^T stride (row m holds K[:,m])
#define BLK 512

#define DTc 0.02f
#define W_C (0.5f/63.0f)
#define WM0 (-1.0f/63.0f)
#define WC0 (2.0f - 1.0f/63.0f)
#define DEPS 6.3e-7f

__device__ __forceinline__ float tanh_fast(float x) {
  float e = __expf(2.0f * x);
  return 1.0f - 2.0f / (e + 1.0f);
}

__device__ __forceinline__ void chol_panel32(float* P, int pc, int lane) {
  float pr[32];
  #pragma unroll
  for (int c4 = 0; c4 < 8; ++c4)
    *(float4*)&pr[c4*4] = *(const float4*)&P[lane*PS + pc + c4*4];
  #pragma unroll
  for (int jj = 0; jj < 32; ++jj) {
    const int gc = pc + jj;
    float dv  = __shfl(pr[jj], gc);
    float inv = rsqrtf(dv);
    pr[jj] = (lane == gc) ? dv * inv : ((lane < gc) ? 0.f : pr[jj] * inv);
    #pragma unroll
    for (int kk = jj + 1; kk < 32; ++kk) {
      float ck = __shfl(pr[jj], pc + kk);
      pr[kk] = fmaf(-pr[jj], ck, pr[kk]);
    }
  }
  #pragma unroll
  for (int c4 = 0; c4 < 8; ++c4)
    *(float4*)&P[lane*PS + pc + c4*4] = *(const float4*)&pr[c4*4];
}

__global__ __launch_bounds__(BLK)
void ukf_main(const float* __restrict__ Xg, const float* __restrict__ Yg,
              const float* __restrict__ Fg, const float* __restrict__ Hg,
              const float* __restrict__ Qg, const float* __restrict__ Rg,
              float* __restrict__ outX, float* __restrict__ outP,
              float* __restrict__ wsPart)
{
  __shared__ __align__(16) float P[NS*PS];      // 17408 B
  __shared__ __align__(16) float sfb[128*SFS];  // 34816 B: F^T+FL+sigma; overlays
  __shared__ __align__(16) float sHT[NS*HTS];   // 9216 B
  __shared__ __align__(16) float sPart[8*NS];   // 2048 B
  __shared__ __align__(16) float sx[NS];
  __shared__ __align__(16) float sxp[NS];
  __shared__ __align__(16) float sFx[NS];
  __shared__ __align__(16) float s0[NS];
  __shared__ __align__(16) float sd0[NS];
  __shared__ __align__(16) float sinn[NO];

  // overlays on sfb (live only after sigma data is consumed):
  float* Tb  = sfb;          // [0,    2176): 32 x TS
  float* Pzb = sfb + 2176;   // [2176, 4352): 32 x GJS
  float* Pzi = sfb + 4352;   // [4352, 5504): 32 x PZS (col-major inverse)
  float* Ktb = sfb + 5504;   // [5504, 7680): 32 x KTS (K transposed)

  const int tid  = threadIdx.x;
  const int lane = tid & 63;
  const int grp  = tid >> 6;
  const int traj = blockIdx.x;

  for (int o = tid; o < NS*NS; o += BLK) {
    int i = o >> 6, j = o & 63;
    P[i*PS + j] = (i == j) ? (63e-5f + DEPS) : 0.f;
  }
  for (int o = tid; o < NO*NS; o += BLK) {
    int m = o >> 6, j = o & 63;
    sHT[j*HTS + m] = Hg[o];
  }
  if (tid < NS) sx[tid] = 0.f;
  float errAcc = 0.f;
  __syncthreads();

  for (int t = 0; t < TSTEPS; ++t) {
    const size_t sbase = (size_t)traj*TSTEPS + t;

    // ---- A: panel0 (w0) || stage F^T (w1-7) -----------------------------
    if (grp == 0) {
      chol_panel32(P, 0, lane);
    } else {
      for (int c = tid - 64; c < 1024; c += (BLK - 64)) {
        int i = c >> 4, j0 = (c & 15) << 2;
        float4 fv = *(const float4*)&Fg[i*64 + j0];
        sfb[(j0    )*SFS + i] = fv.x;
        sfb[(j0 + 1)*SFS + i] = fv.y;
        sfb[(j0 + 2)*SFS + i] = fv.z;
        sfb[(j0 + 3)*SFS + i] = fv.w;
      }
    }
    __syncthreads();

    // ---- B: rank-32 trailing update on block (32..63)^2 (all 512) -------
    {
      const int k  = 32 + (lane & 31);
      const int ib = 32 + grp*2 + (lane >> 5);
      float Lk[32];
      #pragma unroll
      for (int c4 = 0; c4 < 8; ++c4)
        *(float4*)&Lk[c4*4] = *(const float4*)&P[k*PS + c4*4];
      #pragma unroll
      for (int it = 0; it < 2; ++it) {
        const int i = ib + 16*it;
        float acc = P[i*PS + k];
        #pragma unroll
        for (int c4 = 0; c4 < 8; ++c4) {
          float4 pi = *(const float4*)&P[i*PS + c4*4];   // wave-uniform row
          acc = fmaf(-pi.x, Lk[c4*4    ], acc);
          acc = fmaf(-pi.y, Lk[c4*4 + 1], acc);
          acc = fmaf(-pi.z, Lk[c4*4 + 2], acc);
          acc = fmaf(-pi.w, Lk[c4*4 + 3], acc);
        }
        P[i*PS + k] = acc;
      }
    }
    __syncthreads();

    // ---- C: panel1 (w0) || FL cols 0..31 (w1-6) || Fx (w7) --------------
    if (grp == 0) {
      chol_panel32(P, 32, lane);
    } else if (grp == 7) {
      const int i2 = lane;
      float a2 = 0.f;
      for (int jj = 0; jj < NS; ++jj) a2 = fmaf(sfb[jj*SFS + i2], sx[jj], a2);
      sFx[i2] = a2;
    } else {
      const int widx = tid - 64;                 // 0..383
      for (int itm = widx; itm < 512; itm += 384) {
        const int c  = itm >> 4;                 // 0..31
        const int j0 = (itm & 15) << 2;
        float ax = 0.f, ay = 0.f, az = 0.f, aw = 0.f;
        for (int jj = 0; jj < NS; ++jj) {
          float4 fv = *(const float4*)&sfb[jj*SFS + j0];  // F[j0..+3][jj]
          float lv  = P[jj*PS + c];                       // L[jj][c] (upper=0)
          ax = fmaf(lv, fv.x, ax); ay = fmaf(lv, fv.y, ay);
          az = fmaf(lv, fv.z, az); aw = fmaf(lv, fv.w, aw);
        }
        float4 w4; w4.x = ax; w4.y = ay; w4.z = az; w4.w = aw;
        *(float4*)&sfb[(64 + c)*SFS + j0] = w4;           // FL col c
      }
    }
    __syncthreads();

    // ---- D: FL cols 32..63 (all 512, 32-deep) ---------------------------
    {
      const int c  = 32 + (tid >> 4);
      const int j0 = (tid & 15) << 2;
      float ax = 0.f, ay = 0.f, az = 0.f, aw = 0.f;
      for (int jj = 32; jj < NS; ++jj) {
        float4 fv = *(const float4*)&sfb[jj*SFS + j0];
        float lv  = P[jj*PS + c];
        ax = fmaf(lv, fv.x, ax); ay = fmaf(lv, fv.y, ay);
        az = fmaf(lv, fv.z, az); aw = fmaf(lv, fv.w, aw);
      }
      float4 w4; w4.x = ax; w4.y = ay; w4.z = az; w4.w = aw;
      *(float4*)&sfb[(64 + c)*SFS + j0] = w4;
    }
    __syncthreads();

    // ---- E: sigma points + x_pred partials (all 512) --------------------
    {
      const int j = lane;
      float psum = 0.f;
      float xv = sx[j], fxv = sFx[j];
      for (int cc = grp; cc < NS; cc += 8) {
        float flv = sfb[(64 + cc)*SFS + j];
        float Lv  = P[j*PS + cc];
        float vp = xv + Lv + DTc * tanh_fast(fxv + flv);
        float vm = xv - Lv + DTc * tanh_fast(fxv - flv);
        sfb[cc*SFS + j]        = vp;
        sfb[(64 + cc)*SFS + j] = vm;
        psum += vp + vm;
      }
      sPart[grp*NS + j] = psum;
    }
    if (tid < NS) s0[tid] = sx[tid] + DTc * tanh_fast(sFx[tid]);
    __syncthreads();

    // ---- F: combine + center (all 512; xp per column-group, redundant) --
    {
      const int r  = tid >> 4;                   // 0..31
      const int j0 = (tid & 15) << 2;
      float4 s0r = *(const float4*)&s0[j0];
      float sx_ = 0.f, sy_ = 0.f, sz_ = 0.f, sw_ = 0.f;
      #pragma unroll
      for (int g = 0; g < 8; ++g) {
        float4 p = *(const float4*)&sPart[g*NS + j0];
        sx_ += p.x; sy_ += p.y; sz_ += p.z; sw_ += p.w;
      }
      float4 xp;
      xp.x = fmaf(W_C, sx_, WM0 * s0r.x);
      xp.y = fmaf(W_C, sy_, WM0 * s0r.y);
      xp.z = fmaf(W_C, sz_, WM0 * s0r.z);
      xp.w = fmaf(W_C, sw_, WM0 * s0r.w);
      #pragma unroll
      for (int q = 0; q < 4; ++q) {
        const int row = r + (q << 5);            // 0..127
        float4 v = *(const float4*)&sfb[row*SFS + j0];
        v.x -= xp.x; v.y -= xp.y; v.z -= xp.z; v.w -= xp.w;
        *(float4*)&sfb[row*SFS + j0] = v;
      }
      if (r == 0) *(float4*)&sxp[j0] = xp;
      if (r == 1) {
        float4 d; d.x = s0r.x - xp.x; d.y = s0r.y - xp.y;
        d.z = s0r.z - xp.z; d.w = s0r.w - xp.w;
        *(float4*)&sd0[j0] = d;
      }
    }
    __syncthreads();

    // ---- G: Pn (Q-less) 2x4 tiles (all 512) -----------------------------
    {
      const int i0 = (tid >> 4) << 1;            // 0..62
      const int j0 = (tid & 15) << 2;
      float a0x=0.f,a0y=0.f,a0z=0.f,a0w=0.f, a1x=0.f,a1y=0.f,a1z=0.f,a1w=0.f;
      #pragma unroll 4
      for (int r2 = 0; r2 < 128; ++r2) {
        float2 av = *(const float2*)&sfb[r2*SFS + i0];
        float4 bv = *(const float4*)&sfb[r2*SFS + j0];
        a0x = fmaf(av.x, bv.x, a0x); a0y = fmaf(av.x, bv.y, a0y);
        a0z = fmaf(av.x, bv.z, a0z); a0w = fmaf(av.x, bv.w, a0w);
        a1x = fmaf(av.y, bv.x, a1x); a1y = fmaf(av.y, bv.y, a1y);
        a1z = fmaf(av.y, bv.z, a1z); a1w = fmaf(av.y, bv.w, a1w);
      }
      float2 di = *(const float2*)&sd0[i0];
      float4 dj = *(const float4*)&sd0[j0];
      float d0 = WC0 * di.x, d1 = WC0 * di.y;
      float4 w0, w1;
      w0.x = fmaf(d0, dj.x, W_C * a0x); w0.y = fmaf(d0, dj.y, W_C * a0y);
      w0.z = fmaf(d0, dj.z, W_C * a0z); w0.w = fmaf(d0, dj.w, W_C * a0w);
      w1.x = fmaf(d1, dj.x, W_C * a1x); w1.y = fmaf(d1, dj.y, W_C * a1y);
      w1.z = fmaf(d1, dj.z, W_C * a1z); w1.w = fmaf(d1, dj.w, W_C * a1w);
      *(float4*)&P[(i0    )*PS + j0] = w0;
      *(float4*)&P[(i0 + 1)*PS + j0] = w1;
    }
    __syncthreads();

    // ---- H: T = H @ Pn (all 512; 1x4 outputs) ---------------------------
    {
      const int m  = tid >> 4;                   // 0..31
      const int c0 = (tid & 15) << 2;
      float ax = 0.f, ay = 0.f, az = 0.f, aw = 0.f;
      for (int jj = 0; jj < NS; ++jj) {
        float hv  = sHT[jj*HTS + m];
        float4 pv = *(const float4*)&P[jj*PS + c0];
        ax = fmaf(hv, pv.x, ax); ay = fmaf(hv, pv.y, ay);
        az = fmaf(hv, pv.z, az); aw = fmaf(hv, pv.w, aw);
      }
      float4 w4; w4.x = ax; w4.y = ay; w4.z = az; w4.w = aw;
      *(float4*)&Tb[m*TS + c0] = w4;
    }
    __syncthreads();

    // ---- I: Pz = T @ H^T + R (all 512; 1x2 outputs) ---------------------
    {
      const int m  = tid >> 4;                   // 0..31
      const int n0 = (tid & 15) << 1;            // 0..30
      float2 rv = *(const float2*)&Rg[m*NO + n0];
      float a0 = rv.x, a1 = rv.y;
      for (int jj = 0; jj < NS; ++jj) {
        float tv  = Tb[m*TS + jj];
        float2 hv = *(const float2*)&sHT[jj*HTS + n0];
        a0 = fmaf(tv, hv.x, a0);
        a1 = fmaf(tv, hv.y, a1);
      }
      float2 w2; w2.x = a0; w2.y = a1;
      *(float2*)&Pzb[m*GJS + n0] = w2;
    }
    __syncthreads();

    // ---- J: GJ inverse (w0) || innovation (w1) || P += Q (w2-7) ---------
    if (grp == 0) {
      const int c = lane;
      float w[NO];
      #pragma unroll
      for (int r = 0; r < NO; ++r)
        w[r] = (c < NO) ? Pzb[r*GJS + c] : ((c - NO == r) ? 1.f : 0.f);
      #pragma unroll
      for (int p = 0; p < NO; ++p) {
        float piv = __shfl(w[p], p);
        float rp  = 1.0f / piv;
        float wp  = w[p] * rp;
        #pragma unroll
        for (int r = 0; r < NO; ++r) {
          if (r == p) continue;
          float cr = __shfl(w[r], p);
          w[r] = fmaf(-cr, wp, w[r]);
        }
        w[p] = wp;
      }
      if (c >= NO) {
        #pragma unroll
        for (int r = 0; r < NO; ++r) Pzi[(c - NO)*PZS + r] = w[r];
      }
    } else if (grp == 1) {
      if (lane < NO) {
        float z = 0.f;
        for (int jj = 0; jj < NS; ++jj) z = fmaf(sHT[jj*HTS + lane], sxp[jj], z);
        sinn[lane] = Yg[sbase*NO + lane] - z;
      }
    } else {
      const int idx = tid - 128;                 // 0..383
      for (int it = idx; it < 1024; it += 384) {
        const int i = it >> 4, j0 = (it & 15) << 2;
        float4 q = *(const float4*)&Qg[i*64 + j0];
        float4 p = *(const float4*)&P[i*PS + j0];
        p.x += q.x; p.y += q.y; p.z += q.z; p.w += q.w;
        *(float4*)&P[i*PS + j0] = p;
      }
    }
    __syncthreads();

    // ---- K: K = Pxz @ Pzinv, stored transposed (all 512; 4x1 col) -------
    {
      const int i0 = (tid & 15) << 2;            // state rows i0..i0+3
      const int cb = tid >> 4;                   // obs col 0..31
      float ax = 0.f, ay = 0.f, az = 0.f, aw = 0.f;
      for (int m = 0; m < NO; ++m) {
        float4 tv = *(const float4*)&Tb[m*TS + i0];   // Pxz[i0..+3][m]
        float zv  = Pzi[cb*PZS + m];                  // Pzinv[m][cb]
        ax = fmaf(tv.x, zv, ax); ay = fmaf(tv.y, zv, ay);
        az = fmaf(tv.z, zv, az); aw = fmaf(tv.w, zv, aw);
      }
      float4 w4; w4.x = ax; w4.y = ay; w4.z = az; w4.w = aw;
      *(float4*)&Ktb[cb*KTS + i0] = w4;              // Kt[cb][i0..+3]
    }
    __syncthreads();

    // ---- L: M full (2x4 tiles) fused with P_new/outP; x_new on w0 -------
    {
      const int i0 = (tid >> 4) << 1;            // 0..62
      const int j0 = (tid & 15) << 2;
      float a0x=0.f,a0y=0.f,a0z=0.f,a0w=0.f, a1x=0.f,a1y=0.f,a1z=0.f,a1w=0.f;
      for (int m = 0; m < NO; ++m) {
        float2 ka = *(const float2*)&Ktb[m*KTS + i0];  // K[i0..i0+1][m]
        float4 tb = *(const float4*)&Tb[m*TS + j0];    // Pxz[j0..+3][m]
        a0x = fmaf(ka.x, tb.x, a0x); a0y = fmaf(ka.x, tb.y, a0y);
        a0z = fmaf(ka.x, tb.z, a0z); a0w = fmaf(ka.x, tb.w, a0w);
        a1x = fmaf(ka.y, tb.x, a1x); a1y = fmaf(ka.y, tb.y, a1y);
        a1z = fmaf(ka.y, tb.z, a1z); a1w = fmaf(ka.y, tb.w, a1w);
      }
      float4 p0 = *(const float4*)&P[(i0    )*PS + j0];  // Pn + Q
      float4 p1 = *(const float4*)&P[(i0 + 1)*PS + j0];
      float4 g0, g1;
      g0.x = p0.x - a0x; g0.y = p0.y - a0y; g0.z = p0.z - a0z; g0.w = p0.w - a0w;
      g1.x = p1.x - a1x; g1.y = p1.y - a1y; g1.z = p1.z - a1z; g1.w = p1.w - a1w;
      float* op = &outP[sbase*(size_t)(NS*NS)];
      *(float4*)&op[(i0    )*64 + j0] = g0;
      *(float4*)&op[(i0 + 1)*64 + j0] = g1;
      float4 s0w, s1w;
      s0w.x = fmaf(g0.x, 63.f, (i0     == j0    ) ? DEPS : 0.f);
      s0w.y = fmaf(g0.y, 63.f, (i0     == j0 + 1) ? DEPS : 0.f);
      s0w.z = fmaf(g0.z, 63.f, (i0     == j0 + 2) ? DEPS : 0.f);
      s0w.w = fmaf(g0.w, 63.f, (i0     == j0 + 3) ? DEPS : 0.f);
      s1w.x = fmaf(g1.x, 63.f, (i0 + 1 == j0    ) ? DEPS : 0.f);
      s1w.y = fmaf(g1.y, 63.f, (i0 + 1 == j0 + 1) ? DEPS : 0.f);
      s1w.z = fmaf(g1.z, 63.f, (i0 + 1 == j0 + 2) ? DEPS : 0.f);
      s1w.w = fmaf(g1.w, 63.f, (i0 + 1 == j0 + 3) ? DEPS : 0.f);
      *(float4*)&P[(i0    )*PS + j0] = s0w;
      *(float4*)&P[(i0 + 1)*PS + j0] = s1w;
    }
    if (tid < NS) {                              // x_new on wave0 (extra job)
      const int i = tid;
      float xn = sxp[i];
      #pragma unroll 8
      for (int m = 0; m < NO; ++m) xn = fmaf(Ktb[m*KTS + i], sinn[m], xn);
      sx[i] = xn;
      outX[sbase*NS + i] = xn;
      float dd = xn - Xg[sbase*NS + i];
      errAcc = fmaf(dd, dd, errAcc);
    }
    __syncthreads();
  }

  // ---- per-trajectory squared-error total (err lives on wave0)
  if (grp == 0) {
    float v = errAcc;
    for (int off = 32; off > 0; off >>= 1) v += __shfl_down(v, off);
    if (lane == 0) wsPart[traj] = v;
  }
}

__global__ __launch_bounds__(128)
void mse_reduce(const float* __restrict__ part, float* __restrict__ outS)
{
  __shared__ float sbuf[128];
  int tid = threadIdx.x;
  sbuf[tid] = part[tid];
  __syncthreads();
  if (tid < 64) {
    float v = sbuf[tid] + sbuf[tid + 64];
    for (int off = 32; off > 0; off >>= 1) v += __shfl_down(v, off);
    if (tid == 0) {
      float m = v / (128.f * 250.f * 64.f);
      outS[0] = m;
      outS[1] = 10.f * log10f(m);
    }
  }
}

extern "C" void kernel_launch(void* const* d_in, const int* in_sizes, int n_in,
                              void* d_out, int out_size, void* d_ws, size_t ws_size,
                              hipStream_t stream) {
  const float* Xg = (const float*)d_in[0];
  const float* Yg = (const float*)d_in[1];
  const float* Fg = (const float*)d_in[2];
  const float* Hg = (const float*)d_in[3];
  const float* Qg = (const float*)d_in[4];
  const float* Rg = (const float*)d_in[5];

  float* outX = (float*)d_out;                                   // 128*250*64
  float* outP = outX + (size_t)NTRAJ*TSTEPS*NS;                  // 128*250*64*64
  float* outS = outP + (size_t)NTRAJ*TSTEPS*NS*NS;               // 2 scalars
  float* wsP  = (float*)d_ws;                                    // 128 partials

  hipLaunchKernelGGL(ukf_main, dim3(NTRAJ), dim3(BLK), 0, stream,
                     Xg, Yg, Fg, Hg, Qg, Rg, outX, outP, wsP);
  hipLaunchKernelGGL(mse_reduce, dim3(1), dim3(128), 0, stream, wsP, outS);
}